// Round 1
// baseline (286.532 us; speedup 1.0000x reference)
//
#include <hip/hip_runtime.h>

// GRU (I=2, H=2, T=512, B=32768) + exp(fc(h)) head, fully fused.
// One thread per batch element; entire hidden state + weights in registers.
// x layout [T][B][2] -> per-thread stride B float2's; 8-deep prefetch ring.

__device__ __forceinline__ float fsigmoid(float v) {
    // 1/(1+e^-v) ; exp2/rcp are the HW transcendental ops (~1 ulp)
    float e = __builtin_amdgcn_exp2f(-1.4426950408889634f * v);
    return __builtin_amdgcn_rcpf(1.0f + e);
}
__device__ __forceinline__ float ftanh(float v) {
    // tanh(v) = 1 - 2/(e^{2v}+1)
    float e = __builtin_amdgcn_exp2f(2.885390081777927f * v);
    return 1.0f - 2.0f * __builtin_amdgcn_rcpf(1.0f + e);
}

__global__ __launch_bounds__(64) void gru_fused_kernel(
    const float* __restrict__ x, const float* __restrict__ hx,
    const float* __restrict__ W_ih, const float* __restrict__ W_hh,
    const float* __restrict__ b_ih, const float* __restrict__ b_hh,
    const float* __restrict__ fc_w, const float* __restrict__ fc_b,
    float* __restrict__ out, int Tn, int Bn)
{
    const int b = blockIdx.x * blockDim.x + threadIdx.x;
    if (b >= Bn) return;

    // Uniform weight loads -> scalar loads / SGPRs.
    float wi[12], wh[12];
    #pragma unroll
    for (int i = 0; i < 12; ++i) { wi[i] = W_ih[i]; wh[i] = W_hh[i]; }
    const float br0 = b_ih[0] + b_hh[0], br1 = b_ih[1] + b_hh[1];
    const float bz0 = b_ih[2] + b_hh[2], bz1 = b_ih[3] + b_hh[3];
    const float bin0 = b_ih[4], bin1 = b_ih[5];
    const float bhn0 = b_hh[4], bhn1 = b_hh[5];
    const float fw0 = fc_w[0], fw1 = fc_w[1], fb = fc_b[0];

    float h0 = hx[2*b + 0], h1 = hx[2*b + 1];

    const float2* __restrict__ px = (const float2*)x + b;  // [t] at px[t*Bn]
    float* __restrict__ po = out + b;                      // [t] at po[t*Bn]

    const int D = 8;                 // prefetch depth (Tn must be multiple of D; 512 is)
    float2 ring[D];
    #pragma unroll
    for (int k = 0; k < D; ++k) ring[k] = px[(size_t)k * Bn];

    for (int tb = 0; tb < Tn; tb += D) {
        #pragma unroll
        for (int k = 0; k < D; ++k) {
            const int t = tb + k;
            float2 xc = ring[k];
            int tp = t + D; if (tp > Tn - 1) tp = Tn - 1;   // uniform clamp, branchless tail
            ring[k] = px[(size_t)tp * Bn];

            const float x0 = xc.x, x1 = xc.y;
            // pre-activations (gate order r,z,n per PyTorch)
            float ar0 = br0 + x0*wi[0]  + x1*wi[1]  + h0*wh[0]  + h1*wh[1];
            float ar1 = br1 + x0*wi[2]  + x1*wi[3]  + h0*wh[2]  + h1*wh[3];
            float az0 = bz0 + x0*wi[4]  + x1*wi[5]  + h0*wh[4]  + h1*wh[5];
            float az1 = bz1 + x0*wi[6]  + x1*wi[7]  + h0*wh[6]  + h1*wh[7];
            float gin0 = bin0 + x0*wi[8]  + x1*wi[9];
            float gin1 = bin1 + x0*wi[10] + x1*wi[11];
            float ghn0 = bhn0 + h0*wh[8]  + h1*wh[9];
            float ghn1 = bhn1 + h0*wh[10] + h1*wh[11];

            float r0 = fsigmoid(ar0), r1 = fsigmoid(ar1);
            float z0 = fsigmoid(az0), z1 = fsigmoid(az1);
            float n0 = ftanh(gin0 + r0*ghn0);
            float n1 = ftanh(gin1 + r1*ghn1);
            h0 = n0 + z0*(h0 - n0);
            h1 = n1 + z1*(h1 - n1);

            float o = __builtin_amdgcn_exp2f(1.4426950408889634f * (fb + h0*fw0 + h1*fw1));
            po[(size_t)t * Bn] = o;
        }
    }

    // final hidden state: d_out[T*B + b*2 + j]
    float2* ph = (float2*)(out + (size_t)Tn * Bn);
    ph[b] = make_float2(h0, h1);
}

extern "C" void kernel_launch(void* const* d_in, const int* in_sizes, int n_in,
                              void* d_out, int out_size, void* d_ws, size_t ws_size,
                              hipStream_t stream) {
    const float* x    = (const float*)d_in[0];
    const float* hx   = (const float*)d_in[1];
    const float* W_ih = (const float*)d_in[2];
    const float* W_hh = (const float*)d_in[3];
    const float* b_ih = (const float*)d_in[4];
    const float* b_hh = (const float*)d_in[5];
    const float* fc_w = (const float*)d_in[6];
    const float* fc_b = (const float*)d_in[7];
    float* out = (float*)d_out;

    const int Bn = in_sizes[1] / 2;          // hx is [1,B,2]
    const int Tn = in_sizes[0] / (Bn * 2);   // x is [T,B,2]

    dim3 block(64);
    dim3 grid((Bn + 63) / 64);               // 512 blocks -> 2 waves/CU on 256 CUs
    gru_fused_kernel<<<grid, block, 0, stream>>>(x, hx, W_ih, W_hh, b_ih, b_hh,
                                                 fc_w, fc_b, out, Tn, Bn);
}

// Round 2
// 274.685 us; speedup vs baseline: 1.0431x; 1.0431x over previous
//
#include <hip/hip_runtime.h>

// GRU (I=2, H=2, T=512, B=32768) + exp(fc(h)) head.
// Two lanes per chain: lane j = tid&1 owns hidden unit j. Cross-lane h/x
// exchange via DPP quad_perm lane-xor-1 (no LDS). exp-base conversion
// constants folded into weights at init so every activation is a bare
// v_exp_f32 / v_rcp_f32. 65536 threads = 1024 waves -> 1 wave per SIMD
// across the whole chip (vs 512 waves / half coverage in round 1).

#define L2E 1.4426950408889634f

__device__ __forceinline__ float swap1(float v) {
    // lane-xor-1 within quads: quad_perm(1,0,3,2) = 0xB1
    int i = __builtin_amdgcn_mov_dpp(__float_as_int(v), 0xB1, 0xF, 0xF, true);
    return __int_as_float(i);
}

__global__ __launch_bounds__(64) void gru2_kernel(
    const float* __restrict__ x, const float* __restrict__ hx,
    const float* __restrict__ W_ih, const float* __restrict__ W_hh,
    const float* __restrict__ b_ih, const float* __restrict__ b_hh,
    const float* __restrict__ fc_w, const float* __restrict__ fc_b,
    float* __restrict__ out, int Tn, int Bn)
{
    const int gtid = blockIdx.x * blockDim.x + threadIdx.x;  // = b*2 + j
    const int j  = gtid & 1;          // my hidden unit
    const int oj = j ^ 1;
    const int b  = gtid >> 1;         // my chain

    // Gate rows in PyTorch layout [3H, I]=[6,2]: r=row j, z=row 2+j, n=row 4+j.
    // "own" column = j (pairs with my x/h), "oth" = 1-j (pairs with partner's).
    // Sigmoid args pre-scaled by -log2e; tanh arg by 2*log2e; head by log2e.
    const float wir_o = -L2E * W_ih[j*2 + j],      wir_t = -L2E * W_ih[j*2 + oj];
    const float whr_o = -L2E * W_hh[j*2 + j],      whr_t = -L2E * W_hh[j*2 + oj];
    const float br    = -L2E * (b_ih[j] + b_hh[j]);
    const float wiz_o = -L2E * W_ih[(2+j)*2 + j],  wiz_t = -L2E * W_ih[(2+j)*2 + oj];
    const float whz_o = -L2E * W_hh[(2+j)*2 + j],  whz_t = -L2E * W_hh[(2+j)*2 + oj];
    const float bz    = -L2E * (b_ih[2+j] + b_hh[2+j]);
    const float K = 2.0f * L2E;
    const float win_o = K * W_ih[(4+j)*2 + j],     win_t = K * W_ih[(4+j)*2 + oj];
    const float whn_o = K * W_hh[(4+j)*2 + j],     whn_t = K * W_hh[(4+j)*2 + oj];
    const float bin   = K * b_ih[4+j];
    const float bhn   = K * b_hh[4+j];
    const float fw_o  = L2E * fc_w[j], fw_t = L2E * fc_w[oj], fbb = L2E * fc_b[0];

    float h = hx[gtid];               // hx[0][b][j]

    const int stride = 2 * Bn;        // floats per timestep in x
    const float* __restrict__ px = x + gtid;   // x[t][b][j] at px[t*stride]
    float* __restrict__ po = out + b;          // out[t][b][0] at po[t*Bn]
    const bool wr = (j == 0);

    const int D = 8;                  // prefetch depth; Tn=512 is a multiple
    float ring[D];
    #pragma unroll
    for (int k = 0; k < D; ++k) ring[k] = px[(size_t)k * stride];

    for (int tb = 0; tb < Tn; tb += D) {
        #pragma unroll
        for (int k = 0; k < D; ++k) {
            const int t = tb + k;
            float xo = ring[k];
            int tp = t + D; if (tp > Tn - 1) tp = Tn - 1;   // branchless tail
            ring[k] = px[(size_t)tp * stride];

            float xt = swap1(xo);     // partner's x
            float ht = swap1(h);      // partner's h

            float ar = fmaf(xo, wir_o, fmaf(xt, wir_t, fmaf(h, whr_o, fmaf(ht, whr_t, br))));
            float az = fmaf(xo, wiz_o, fmaf(xt, wiz_t, fmaf(h, whz_o, fmaf(ht, whz_t, bz))));
            float gn = fmaf(xo, win_o, fmaf(xt, win_t, bin));
            float gh = fmaf(h,  whn_o, fmaf(ht, whn_t, bhn));

            // sigmoid(v) = rcp(1 + exp2(-L2E*v)); args already pre-scaled
            float r = __builtin_amdgcn_rcpf(1.0f + __builtin_amdgcn_exp2f(ar));
            float z = __builtin_amdgcn_rcpf(1.0f + __builtin_amdgcn_exp2f(az));
            // tanh(a) = 1 - 2*rcp(1 + exp2(2*L2E*a)); gn/gh pre-scaled by K
            float a = fmaf(r, gh, gn);
            float n = fmaf(-2.0f, __builtin_amdgcn_rcpf(1.0f + __builtin_amdgcn_exp2f(a)), 1.0f);
            h = fmaf(z, h - n, n);    // (1-z)*n + z*h

            float h2 = swap1(h);      // partner's new h for the head
            float o  = __builtin_amdgcn_exp2f(fmaf(h, fw_o, fmaf(h2, fw_t, fbb)));
            if (wr) po[(size_t)t * Bn] = o;
        }
    }

    // final hidden state: d_out[T*B + b*2 + j] = d_out[T*B + gtid]
    out[(size_t)Tn * Bn + gtid] = h;
}

extern "C" void kernel_launch(void* const* d_in, const int* in_sizes, int n_in,
                              void* d_out, int out_size, void* d_ws, size_t ws_size,
                              hipStream_t stream) {
    const float* x    = (const float*)d_in[0];
    const float* hx   = (const float*)d_in[1];
    const float* W_ih = (const float*)d_in[2];
    const float* W_hh = (const float*)d_in[3];
    const float* b_ih = (const float*)d_in[4];
    const float* b_hh = (const float*)d_in[5];
    const float* fc_w = (const float*)d_in[6];
    const float* fc_b = (const float*)d_in[7];
    float* out = (float*)d_out;

    const int Bn = in_sizes[1] / 2;          // hx is [1,B,2]
    const int Tn = in_sizes[0] / (Bn * 2);   // x is [T,B,2]

    const int threads = Bn * 2;              // 2 lanes per chain
    dim3 block(64);
    dim3 grid(threads / 64);                 // 1024 waves -> 1 per SIMD chip-wide
    gru2_kernel<<<grid, block, 0, stream>>>(x, hx, W_ih, W_hh, b_ih, b_hh,
                                            fc_w, fc_b, out, Tn, Bn);
}

// Round 3
// 220.136 us; speedup vs baseline: 1.3016x; 1.2478x over previous
//
#include <hip/hip_runtime.h>

// GRU (I=2, H=2, T=512, B=32768) + exp(fc(h)) head.
// Two lanes per chain (lane j = gtid&1 owns hidden unit j; DPP lane-xor-1
// exchange). x is staged global->LDS with __builtin_amdgcn_global_load_lds
// (48-row ring = 3 chunks of 16 timesteps, 12KB) and manual
// s_waitcnt vmcnt(32) per chunk, so ~32 steps of memory-latency slack are
// guaranteed regardless of compiler scheduling (round-2 register ring was
// collapsed by the compiler to depth ~1 => 553 cy/step, memory-stall bound).
// exp-base constants folded into weights; activations are bare v_exp/v_rcp.

#define L2E 1.4426950408889634f

__device__ __forceinline__ float swap1(float v) {
    // lane-xor-1 within quads: quad_perm(1,0,3,2) = 0xB1
    int i = __builtin_amdgcn_mov_dpp(__float_as_int(v), 0xB1, 0xF, 0xF, true);
    return __int_as_float(i);
}

__device__ __forceinline__ void async_ld(const float* g, const float* l) {
    // per-lane global addr g; LDS dest = wave-uniform base + lane*4
    __builtin_amdgcn_global_load_lds(
        (const __attribute__((address_space(1))) void*)g,
        (__attribute__((address_space(3))) void*)l, 4, 0, 0);
}

// s_waitcnt simm16 (gfx9 enc): vmcnt[3:0]=s[3:0], vmcnt[5:4]=s[15:14],
// expcnt=s[6:4], lgkmcnt=s[11:8]
#define WAIT_VM32  0x8F70   // vmcnt(32), lgkm/exp = no-wait
#define WAIT_LGKM0 0xC07F   // lgkmcnt(0), vm/exp = no-wait

__global__ __launch_bounds__(64) void gru3_kernel(
    const float* __restrict__ x, const float* __restrict__ hx,
    const float* __restrict__ W_ih, const float* __restrict__ W_hh,
    const float* __restrict__ b_ih, const float* __restrict__ b_hh,
    const float* __restrict__ fc_w, const float* __restrict__ fc_b,
    float* __restrict__ out, int Tn, int Bn)
{
    __shared__ float xs[48 * 64];      // 48 rows x 64 lanes = 12KB, 3-chunk ring

    const int lane = threadIdx.x;
    const int gtid = blockIdx.x * 64 + lane;   // = b*2 + j
    const int j  = gtid & 1;
    const int oj = j ^ 1;
    const int b  = gtid >> 1;
    const int gbase = blockIdx.x * 64;         // element offset within a row
    const int stride = 2 * Bn;                 // floats per timestep of x

    // ---- start the DMA pipeline immediately (rows 0..47) ----
    #pragma unroll
    for (int s = 0; s < 48; ++s)
        async_ld(x + (size_t)s * stride + gbase + lane, &xs[s << 6]);

    // ---- per-lane weight prep (one-time), exp-base constants folded ----
    const float wir_o = -L2E * W_ih[j*2 + j],      wir_t = -L2E * W_ih[j*2 + oj];
    const float whr_o = -L2E * W_hh[j*2 + j],      whr_t = -L2E * W_hh[j*2 + oj];
    const float br    = -L2E * (b_ih[j] + b_hh[j]);
    const float wiz_o = -L2E * W_ih[(2+j)*2 + j],  wiz_t = -L2E * W_ih[(2+j)*2 + oj];
    const float whz_o = -L2E * W_hh[(2+j)*2 + j],  whz_t = -L2E * W_hh[(2+j)*2 + oj];
    const float bz    = -L2E * (b_ih[2+j] + b_hh[2+j]);
    const float K = 2.0f * L2E;
    const float win_o = K * W_ih[(4+j)*2 + j],     win_t = K * W_ih[(4+j)*2 + oj];
    const float whn_o = K * W_hh[(4+j)*2 + j],     whn_t = K * W_hh[(4+j)*2 + oj];
    const float bin   = K * b_ih[4+j];
    const float bhn   = K * b_hh[4+j];
    const float fw_o  = L2E * fc_w[j], fw_t = L2E * fc_w[oj], fbb = L2E * fc_b[0];

    float h  = hx[gtid];
    float ht = swap1(h);

    float* po = out + b;               // out[t][b] at po, advance by Bn per step
    const int NC = Tn >> 4;            // chunks of 16 timesteps

    #pragma unroll 1
    for (int c = 0; c < NC; ++c) {
        // rows of this chunk are the oldest >32 outstanding vm ops -> done
        __builtin_amdgcn_s_waitcnt(WAIT_VM32);
        __builtin_amdgcn_sched_barrier(0);

        const int sb = (c % 3) << 10;  // slot base (floats): (c%3)*16*64

        // x-only gate projections for the 16 steps (off the h critical path)
        float rx[16], zx[16], nxx[16];
        #pragma unroll
        for (int i = 0; i < 16; ++i) {
            float xo = xs[sb + (i << 6) + lane];
            float xt = swap1(xo);
            rx[i]  = fmaf(xo, wir_o, fmaf(xt, wir_t, br));
            zx[i]  = fmaf(xo, wiz_o, fmaf(xt, wiz_t, bz));
            nxx[i] = fmaf(xo, win_o, fmaf(xt, win_t, bin));
        }

        // all LDS reads of this chunk complete before DMA may overwrite slots
        __builtin_amdgcn_s_waitcnt(WAIT_LGKM0);
        __builtin_amdgcn_sched_barrier(0);

        // refill the same slots with rows t+48 (clamped dummy loads keep the
        // per-chunk vm-op count invariant for the vmcnt bookkeeping)
        {
            const int t2 = (c + 3) << 4;
            #pragma unroll
            for (int i = 0; i < 16; ++i) {
                int tc = t2 + i; if (tc > Tn - 1) tc = Tn - 1;
                async_ld(x + (size_t)tc * stride + gbase + lane, &xs[sb + (i << 6)]);
            }
        }

        // serial GRU: only the h-dependent work is on the chain
        #pragma unroll
        for (int i = 0; i < 16; ++i) {
            float ar = fmaf(h, whr_o, fmaf(ht, whr_t, rx[i]));
            float az = fmaf(h, whz_o, fmaf(ht, whz_t, zx[i]));
            float gh = fmaf(h, whn_o, fmaf(ht, whn_t, bhn));
            float r = __builtin_amdgcn_rcpf(1.0f + __builtin_amdgcn_exp2f(ar));
            float z = __builtin_amdgcn_rcpf(1.0f + __builtin_amdgcn_exp2f(az));
            float a = fmaf(r, gh, nxx[i]);
            float n = fmaf(-2.0f, __builtin_amdgcn_rcpf(1.0f + __builtin_amdgcn_exp2f(a)), 1.0f);
            h  = fmaf(z, h - n, n);            // (1-z)*n + z*h
            ht = swap1(h);                     // partner h: output now, gates next step
            float o = __builtin_amdgcn_exp2f(fmaf(h, fw_o, fmaf(ht, fw_t, fbb)));
            // both lanes of a pair compute identical o; same-addr same-data store
            *po = o; po += Bn;
        }
    }

    // final hidden state: d_out[T*B + b*2 + j]
    out[(size_t)Tn * Bn + gtid] = h;
}

extern "C" void kernel_launch(void* const* d_in, const int* in_sizes, int n_in,
                              void* d_out, int out_size, void* d_ws, size_t ws_size,
                              hipStream_t stream) {
    const float* x    = (const float*)d_in[0];
    const float* hx   = (const float*)d_in[1];
    const float* W_ih = (const float*)d_in[2];
    const float* W_hh = (const float*)d_in[3];
    const float* b_ih = (const float*)d_in[4];
    const float* b_hh = (const float*)d_in[5];
    const float* fc_w = (const float*)d_in[6];
    const float* fc_b = (const float*)d_in[7];
    float* out = (float*)d_out;

    const int Bn = in_sizes[1] / 2;          // hx is [1,B,2]
    const int Tn = in_sizes[0] / (Bn * 2);   // x is [T,B,2]

    const int threads = Bn * 2;              // 2 lanes per chain
    dim3 block(64);
    dim3 grid(threads / 64);                 // 1024 single-wave blocks
    gru3_kernel<<<grid, block, 0, stream>>>(x, hx, W_ih, W_hh, b_ih, b_hh,
                                            fc_w, fc_b, out, Tn, Bn);
}